// Round 10
// baseline (168.813 us; speedup 1.0000x reference)
//
#include <hip/hip_runtime.h>
#include <hip/hip_bf16.h>
#include <math.h>
#include <stddef.h>

// Problem shape: z [4,64,16,32,32] fp32, embedding [1024,64] fp32
#define CH     64
#define DHWC   16384
#define NTOK   65536
#define KCODES 1024
#define OUT_ELEMS 4194304

typedef _Float16 f16;
typedef f16  f16x8  __attribute__((ext_vector_type(8)));
typedef float fltx4 __attribute__((ext_vector_type(4)));

struct Ws {
  // ---- zeroed header (memset range = offsetof(Ws, e_norm)) ----
  double sum_z2, sum_e2, loss_sum, pad;
  float  sum_z[CH];               // native f32 atomics from gemm h==0 blocks
  double sum_e[CH];
  int    counts[KCODES];
  // ---- filled by eprep ----
  float  e_norm[KCODES];
  float  accI[KCODES + 16];       // -e_norm/2; +16 pad for B-prefetch
  // codebook pre-swizzled into MFMA B-fragment order (R9-verified):
  // e_frag[ct][b01][lane] = the f16x8 lane (nn=lane&15, quad=lane>>4) consumes
  // for code k=ct*16+nn, channels b01*32 + quad*8 + [0,8). +1 pad ct row.
  f16    e_frag[(64 + 1) * 2 * 64 * 8];
  // ---- per-half exact winners (gemm -> writer) ----
  float          hd[2 * NTOK];
  unsigned short hk[2 * NTOK];
};

// ---- eprep: e_norm (exact R1 chain) + channel sums + sum_e2 + fragments --
__global__ void vq_eprep(const float* __restrict__ emb, Ws* __restrict__ ws) {
  __shared__ float tile[64][68];
  __shared__ float red[256];
  const int tid = threadIdx.x;
  const int r = tid >> 2;                 // code row within block (0..63)
  const int q = tid & 3;                  // quarter of the 64-channel row
  const int k = blockIdx.x * 64 + r;
  const float4* src = (const float4*)(emb + (size_t)k * CH + q * 16);
  float4 a = src[0], b = src[1], c = src[2], d = src[3];
  float4* dst = (float4*)(&tile[r][q * 16]);
  dst[0] = a; dst[1] = b; dst[2] = c; dst[3] = d;
  float s2 = 0.f;
  s2 = fmaf(a.x,a.x,s2); s2 = fmaf(a.y,a.y,s2); s2 = fmaf(a.z,a.z,s2); s2 = fmaf(a.w,a.w,s2);
  s2 = fmaf(b.x,b.x,s2); s2 = fmaf(b.y,b.y,s2); s2 = fmaf(b.z,b.z,s2); s2 = fmaf(b.w,b.w,s2);
  s2 = fmaf(c.x,c.x,s2); s2 = fmaf(c.y,c.y,s2); s2 = fmaf(c.z,c.z,s2); s2 = fmaf(c.w,c.w,s2);
  s2 = fmaf(d.x,d.x,s2); s2 = fmaf(d.y,d.y,s2); s2 = fmaf(d.z,d.z,s2); s2 = fmaf(d.w,d.w,s2);
  // verified-exact row norm (R1-R9: absmax 0.0)
  float t1 = s2 + __shfl_xor(s2, 1);
  float t2 = t1 + __shfl_xor(t1, 2);
  if (q == 0) { ws->e_norm[k] = t2; ws->accI[k] = -0.5f * t2; }
  // pre-swizzled B-fragment write (R9-verified)
  {
    float vals[16] = {a.x,a.y,a.z,a.w, b.x,b.y,b.z,b.w,
                      c.x,c.y,c.z,c.w, d.x,d.y,d.z,d.w};
    const int ct  = blockIdx.x * 4 + (r >> 4);
    const int nn  = r & 15;
    const int b01 = q >> 1;
    const int qd0 = (q & 1) * 2;
    f16 h8a[8], h8b[8];
    #pragma unroll
    for (int u = 0; u < 8; ++u) { h8a[u] = (f16)vals[u]; h8b[u] = (f16)vals[8 + u]; }
    f16x8* fr = (f16x8*)ws->e_frag;
    fr[(ct * 2 + b01) * 64 + (qd0 + 0) * 16 + nn] = *(f16x8*)h8a;
    fr[(ct * 2 + b01) * 64 + (qd0 + 1) * 16 + nn] = *(f16x8*)h8b;
  }
  red[tid] = s2;
  __syncthreads();
  for (int off = 128; off > 0; off >>= 1) {
    if (tid < off) red[tid] += red[tid + off];
    __syncthreads();
  }
  if (tid == 0) atomicAdd(&ws->sum_e2, (double)red[0]);
  if (tid < CH) {
    float cs = 0.f;
    #pragma unroll 8
    for (int rr = 0; rr < 64; ++rr) cs += tile[rr][tid];
    atomicAdd(&ws->sum_e[tid], (double)cs);
  }
}

// ---- phase 1+2: MFMA candidates + exact per-half recheck -----------------
// grid 1024 = (512 token-groups) x (2 K-halves); block = 128 tokens x 512 codes
__global__ __launch_bounds__(256, 4)
void vq_gemm(const float* __restrict__ z, const float* __restrict__ emb,
             Ws* __restrict__ ws) {
  // LDS: [0,18432) zh (f16 z-tile), later reused as cand2 (uint2[128*17]=17408)
  //      [18432,19456) csh  [19456,20480) rd  [20480,21504) rk  [21504,23552) shs
  __shared__ char smem[23552];
  f16*          zh    = (f16*)smem;
  uint2*        cand2 = (uint2*)smem;
  unsigned int* csh   = (unsigned int*)(smem + 18432);
  float*        rd    = (float*)(smem + 19456);
  int*          rk    = (int*)(smem + 20480);
  float*        shs   = (float*)(smem + 21504);   // [512]: s, s2

  const int tid = threadIdx.x;
  const int h   = blockIdx.x & 1;          // K-half
  const int tg  = blockIdx.x >> 1;         // token group
  const int n0  = tg * 128;
  const int b   = n0 >> 14;
  const int s0  = n0 & 16383;
  const float* zbase = z + (size_t)b * (CH * DHWC) + s0;

  // stage z -> f16 [token][c] (stride 72); h==0 blocks also do channel sums
  {
    const int c = tid >> 2;            // 0..63
    const int q = tid & 3;             // token quarter
    const float4* src = (const float4*)(zbase + (size_t)c * DHWC) + q * 8;
    float ss = 0.f, ss2 = 0.f;
    #pragma unroll
    for (int i = 0; i < 8; ++i) {
      float4 v = src[i];
      const int t0 = q * 32 + i * 4;
      zh[(t0 + 0) * 72 + c] = (f16)v.x;
      zh[(t0 + 1) * 72 + c] = (f16)v.y;
      zh[(t0 + 2) * 72 + c] = (f16)v.z;
      zh[(t0 + 3) * 72 + c] = (f16)v.w;
      ss += v.x + v.y + v.z + v.w;
      ss2 = fmaf(v.x, v.x, ss2); ss2 = fmaf(v.y, v.y, ss2);
      ss2 = fmaf(v.z, v.z, ss2); ss2 = fmaf(v.w, v.w, ss2);
    }
    shs[tid] = ss; shs[256 + tid] = ss2;
  }
  __syncthreads();
  if (h == 0 && tid < 64) {
    float cs = shs[4*tid] + shs[4*tid+1] + shs[4*tid+2] + shs[4*tid+3];
    atomicAdd(&ws->sum_z[tid], cs);
    float cs2 = shs[256+4*tid] + shs[256+4*tid+1] + shs[256+4*tid+2] + shs[256+4*tid+3];
    #pragma unroll
    for (int off = 32; off > 0; off >>= 1) cs2 += __shfl_down(cs2, off);
    if (tid == 0) atomicAdd(&ws->sum_z2, (double)cs2);
  }

  const int lane = tid & 63;
  const int w    = tid >> 6;           // wave: tokens [w*32, w*32+32)
  const int nn   = lane & 15;          // MFMA column (code class)
  const int quad = lane >> 4;

  // A fragments (R4-R9-verified layout): A[m=lane&15][k=quad*8+j]
  f16x8 Ah[2][2];
  #pragma unroll
  for (int mt = 0; mt < 2; ++mt) {
    const int row = w * 32 + mt * 16 + nn;
    #pragma unroll
    for (int ks = 0; ks < 2; ++ks)
      Ah[mt][ks] = *(const f16x8*)(&zh[row * 72 + ks * 32 + quad * 8]);
  }

  // per-(token-slot, class) top-2 of (dot - enorm/2); argmax == argmin d
  float m1[8], m2[8]; int k1[8], k2[8];
  #pragma unroll
  for (int u = 0; u < 8; ++u) { m1[u] = -3.4e38f; m2[u] = -3.4e38f; k1[u] = 0; k2[u] = 0; }

  // B-fragments: lane-consecutive 16B -> ONE coalesced transaction per load
  const f16x8* __restrict__ fr  = ((const f16x8*)ws->e_frag) + lane;
  const float* __restrict__ aIp = ws->accI;

  int ct = h * 32;
  f16x8 B0 = fr[(ct * 2 + 0) * 64];
  f16x8 B1 = fr[(ct * 2 + 1) * 64];
  float ai = aIp[ct * 16 + nn];
  #pragma unroll 2
  for (int it = 0; it < 32; ++it) {
    const int nct = ct + 1;            // last prefetch hits the pad row
    f16x8 nB0 = fr[(nct * 2 + 0) * 64];
    f16x8 nB1 = fr[(nct * 2 + 1) * 64];
    const float nai = aIp[nct * 16 + nn];
    const int krow = ct * 16 + nn;
    fltx4 acc0 = {ai, ai, ai, ai};
    acc0 = __builtin_amdgcn_mfma_f32_16x16x32_f16(Ah[0][0], B0, acc0, 0, 0, 0);
    acc0 = __builtin_amdgcn_mfma_f32_16x16x32_f16(Ah[0][1], B1, acc0, 0, 0, 0);
    fltx4 acc1 = {ai, ai, ai, ai};
    acc1 = __builtin_amdgcn_mfma_f32_16x16x32_f16(Ah[1][0], B0, acc1, 0, 0, 0);
    acc1 = __builtin_amdgcn_mfma_f32_16x16x32_f16(Ah[1][1], B1, acc1, 0, 0, 0);
    #pragma unroll
    for (int r = 0; r < 4; ++r) {
      float a = acc0[r]; const int u = r;
      bool c1 = a > m1[u], c2 = a > m2[u];
      m2[u] = c1 ? m1[u] : (c2 ? a : m2[u]);
      k2[u] = c1 ? k1[u] : (c2 ? krow : k2[u]);
      m1[u] = c1 ? a : m1[u];
      k1[u] = c1 ? krow : k1[u];
    }
    #pragma unroll
    for (int r = 0; r < 4; ++r) {
      float a = acc1[r]; const int u = 4 + r;
      bool c1 = a > m1[u], c2 = a > m2[u];
      m2[u] = c1 ? m1[u] : (c2 ? a : m2[u]);
      k2[u] = c1 ? k1[u] : (c2 ? krow : k2[u]);
      m1[u] = c1 ? a : m1[u];
      k1[u] = c1 ? krow : k1[u];
    }
    ct = nct; B0 = nB0; B1 = nB1; ai = nai;
  }

  // pre-merge neighbor classes (lane^1): 16 classes -> 8 pairs, top-2 each
  #pragma unroll
  for (int u = 0; u < 8; ++u) {
    float om1 = __shfl_xor(m1[u], 1), om2 = __shfl_xor(m2[u], 1);
    int   ok1 = __shfl_xor(k1[u], 1), ok2 = __shfl_xor(k2[u], 1);
    bool af = (m1[u] > om1) || (m1[u] == om1 && k1[u] < ok1);
    float w1 = af ? m1[u] : om1;  int wk1 = af ? k1[u] : ok1;
    float s2v = af ? m2[u] : om2; int sk2 = af ? k2[u] : ok2;
    float l1 = af ? om1 : m1[u];  int lk1 = af ? ok1 : k1[u];
    bool sf = (s2v > l1) || (s2v == l1 && sk2 < lk1);
    m1[u] = w1; k1[u] = wk1;
    m2[u] = sf ? s2v : l1; k2[u] = sf ? sk2 : lk1;
  }

  __syncthreads();          // zh reads done; safe to overwrite as cand2
  if (!(nn & 1)) {
    const int p = nn >> 1;
    #pragma unroll
    for (int mt = 0; mt < 2; ++mt)
      #pragma unroll
      for (int r = 0; r < 4; ++r) {
        const int u = mt * 4 + r;
        const int tok = w * 32 + mt * 16 + quad * 4 + r;  // C/D row (verified)
        uint2 e1; e1.x = __float_as_uint(m1[u]); e1.y = (unsigned)k1[u];
        uint2 e2; e2.x = __float_as_uint(m2[u]); e2.y = (unsigned)k2[u];
        cand2[tok * 17 + p * 2 + 0] = e1;
        cand2[tok * 17 + p * 2 + 1] = e2;
      }
  }
  __syncthreads();

  // narrow 16 -> top-4 per token by (value desc, k asc)
  if (tid < 128) {
    float bv[4]; int bk[4];
    #pragma unroll
    for (int u = 0; u < 4; ++u) { bv[u] = -3.4e38f; bk[u] = 0x7fffffff; }
    #pragma unroll 4
    for (int i = 0; i < 16; ++i) {
      uint2 e = cand2[tid * 17 + i];
      float a = __uint_as_float(e.x);
      int   k = (int)e.y;
      #pragma unroll
      for (int j = 0; j < 4; ++j) {
        bool ins = (a > bv[j]) || (a == bv[j] && k < bk[j]);
        float ta = bv[j]; int tk = bk[j];
        bv[j] = ins ? a : bv[j]; bk[j] = ins ? k : bk[j];
        a = ins ? ta : a; k = ins ? tk : k;
      }
    }
    csh[tid * 2 + 0] = (unsigned)bk[0] | ((unsigned)bk[1] << 16);
    csh[tid * 2 + 1] = (unsigned)bk[2] | ((unsigned)bk[3] << 16);
  }
  __syncthreads();

  // exact recheck (R1 chain, R7-verified float4 e-loads): 4x fewer TA probes
  {
    const int t = tid & 127, half = tid >> 7;
    unsigned int cd = csh[t * 2 + half];
    const int ka = (int)(cd & 0xffff), kb = (int)(cd >> 16);
    const float4* ea4 = (const float4*)(emb + (size_t)ka * CH);
    const float4* eb4 = (const float4*)(emb + (size_t)kb * CH);
    const float* zt = zbase + t;
    float znorm = 0.f, da = 0.f, db = 0.f;
    #pragma unroll 4
    for (int c4 = 0; c4 < 16; ++c4) {
      float4 ev = ea4[c4];
      float4 fv = eb4[c4];
      float v0 = zt[(size_t)(4*c4+0) * DHWC];
      float v1 = zt[(size_t)(4*c4+1) * DHWC];
      float v2 = zt[(size_t)(4*c4+2) * DHWC];
      float v3 = zt[(size_t)(4*c4+3) * DHWC];
      znorm = fmaf(v0, v0, znorm); znorm = fmaf(v1, v1, znorm);
      znorm = fmaf(v2, v2, znorm); znorm = fmaf(v3, v3, znorm);
      da = fmaf(v0, ev.x, da); da = fmaf(v1, ev.y, da);
      da = fmaf(v2, ev.z, da); da = fmaf(v3, ev.w, da);
      db = fmaf(v0, fv.x, db); db = fmaf(v1, fv.y, db);
      db = fmaf(v2, fv.z, db); db = fmaf(v3, fv.w, db);
    }
    float dda = fmaf(-2.f, da, znorm + ws->e_norm[ka]);
    float ddb = fmaf(-2.f, db, znorm + ws->e_norm[kb]);
    bool pa = (dda < ddb) || (dda == ddb && ka < kb);
    rd[tid] = pa ? dda : ddb;
    rk[tid] = pa ? ka : kb;
  }
  __syncthreads();
  if (tid < 128) {
    float d0 = rd[tid], d1 = rd[tid + 128];
    int   q0 = rk[tid], q1 = rk[tid + 128];
    bool p = (d0 < d1) || (d0 == d1 && q0 < q1);
    ws->hd[h * NTOK + n0 + tid] = p ? d0 : d1;
    ws->hk[h * NTOK + n0 + tid] = (unsigned short)(p ? q0 : q1);
  }
}

// ---- phase 3: combine halves + output + loss + counts --------------------
// grid 2048 x 256; block = eighth of one (b,c) plane; emb column in LDS
__global__ __launch_bounds__(256, 8)
void vq_writer(const float* __restrict__ z, const float* __restrict__ emb,
               float* __restrict__ out, Ws* __restrict__ ws) {
  __shared__ float ecol[KCODES];     // column c of emb (4 KB)
  __shared__ int   hist[KCODES];     // LDS histogram (c==0 blocks only)
  __shared__ float sh[256];
  const int blk = blockIdx.x;
  const int p   = blk >> 3;          // plane: b*64 + c
  const int e8  = blk & 7;
  const int tid = threadIdx.x;
  const int b = p >> 6, c = p & 63;
  const bool docnt = (c == 0);
  // stage emb column c: converts divergent global gathers -> LDS reads
  #pragma unroll
  for (int i = tid; i < KCODES; i += 256) {
    ecol[i] = emb[(size_t)i * CH + c];
    if (docnt) hist[i] = 0;
  }
  __syncthreads();

  const size_t base = (size_t)p * DHWC + e8 * 2048;
  const float4* zp = (const float4*)(z + base);
  float4* op = (float4*)(out + base);
  const int nbase = b * 16384 + e8 * 2048;
  const float*          hd0 = ws->hd + nbase;
  const float*          hd1 = ws->hd + NTOK + nbase;
  const unsigned short* hk0 = ws->hk + nbase;
  const unsigned short* hk1 = ws->hk + NTOK + nbase;
  float lp = 0.f;
  #pragma unroll
  for (int i = tid; i < 512; i += 256) {           // 2 iterations
    float4 v  = zp[i];
    float4 d0 = *(const float4*)(hd0 + 4 * i);
    float4 d1 = *(const float4*)(hd1 + 4 * i);
    ushort4 ka = *(const ushort4*)(hk0 + 4 * i);
    ushort4 kb = *(const ushort4*)(hk1 + 4 * i);
    int w0 = (d0.x < d1.x || (d0.x == d1.x && ka.x < kb.x)) ? ka.x : kb.x;
    int w1 = (d0.y < d1.y || (d0.y == d1.y && ka.y < kb.y)) ? ka.y : kb.y;
    int w2 = (d0.z < d1.z || (d0.z == d1.z && ka.z < kb.z)) ? ka.z : kb.z;
    int w3 = (d0.w < d1.w || (d0.w == d1.w && ka.w < kb.w)) ? ka.w : kb.w;
    float q0 = ecol[w0], q1 = ecol[w1], q2 = ecol[w2], q3 = ecol[w3];
    float e0 = q0 - v.x, e1 = q1 - v.y, e2 = q2 - v.z, e3 = q3 - v.w;
    float4 o; o.x = v.x + e0; o.y = v.y + e1; o.z = v.z + e2; o.w = v.w + e3;
    op[i] = o;
    lp = fmaf(e0, e0, lp); lp = fmaf(e1, e1, lp);
    lp = fmaf(e2, e2, lp); lp = fmaf(e3, e3, lp);
    if (docnt) {                       // LDS atomics: no global contention
      atomicAdd(&hist[w0], 1);
      atomicAdd(&hist[w1], 1);
      atomicAdd(&hist[w2], 1);
      atomicAdd(&hist[w3], 1);
    }
  }
  sh[tid] = lp;
  __syncthreads();
  if (docnt) {
    #pragma unroll
    for (int i = tid; i < KCODES; i += 256) {
      int h2 = hist[i];
      if (h2) atomicAdd(&ws->counts[i], h2);
    }
  }
  for (int off = 128; off > 0; off >>= 1) {
    if (tid < off) sh[tid] += sh[tid + off];
    __syncthreads();
  }
  if (tid == 0) atomicAdd(&ws->loss_sum, (double)sh[0]);
}

// ---- final: scalars ------------------------------------------------------
__global__ void vq_final(Ws* __restrict__ ws, float* __restrict__ out_scalars) {
  const int tid = threadIdx.x;
  float p = (float)ws->counts[tid] * (1.0f / 65536.0f);
  float term = p * logf(p + 1e-10f);
  __shared__ float sh[1024];
  sh[tid] = term;
  __syncthreads();
  for (int off = 512; off > 0; off >>= 1) {
    if (tid < off) sh[tid] += sh[tid + off];
    __syncthreads();
  }
  if (tid == 0) {
    float perp = expf(-sh[0]);
    double m = ws->loss_sum / (double)OUT_ELEMS;
    float mf = (float)m;
    float loss = mf + 0.25f * mf;
    double sdot = 0.0;
    #pragma unroll
    for (int c = 0; c < CH; ++c) sdot += (double)ws->sum_z[c] * ws->sum_e[c];
    double md = ws->sum_z2 / (double)NTOK + ws->sum_e2 / (double)KCODES
              - 2.0 * sdot / ((double)NTOK * (double)KCODES);
    out_scalars[0] = loss;
    out_scalars[1] = perp;
    out_scalars[2] = (float)md;
  }
}

extern "C" void kernel_launch(void* const* d_in, const int* in_sizes, int n_in,
                              void* d_out, int out_size, void* d_ws, size_t ws_size,
                              hipStream_t stream) {
  const float* z   = (const float*)d_in[0];
  const float* emb = (const float*)d_in[1];
  float* out = (float*)d_out;
  Ws* ws = (Ws*)d_ws;

  hipMemsetAsync(d_ws, 0, offsetof(Ws, e_norm), stream);
  vq_eprep <<<16,   256, 0, stream>>>(emb, ws);
  vq_gemm  <<<1024, 256, 0, stream>>>(z, emb, ws);
  vq_writer<<<2048, 256, 0, stream>>>(z, emb, out, ws);
  vq_final <<<1, 1024, 0, stream>>>(ws, out + OUT_ELEMS);
}

// Round 11
// 145.319 us; speedup vs baseline: 1.1617x; 1.1617x over previous
//
#include <hip/hip_runtime.h>
#include <hip/hip_bf16.h>
#include <math.h>
#include <stddef.h>

// Problem shape: z [4,64,16,32,32] fp32, embedding [1024,64] fp32
#define CH     64
#define DHWC   16384
#define NTOK   65536
#define KCODES 1024
#define OUT_ELEMS 4194304

typedef _Float16 f16;
typedef f16  f16x8  __attribute__((ext_vector_type(8)));
typedef float fltx4 __attribute__((ext_vector_type(4)));

struct Ws {
  // ---- zeroed header (memset range = offsetof(Ws, e_norm)) ----
  double sum_z2, sum_e2, loss_sum, pad;
  float  sum_z[CH];               // native f32 atomics from gemm h==0 blocks
  double sum_e[CH];
  int    counts[KCODES];
  // ---- filled by eprep ----
  float  e_norm[KCODES];
  float  accI[KCODES + 16];       // -e_norm/2; +16 pad for B-prefetch
  // codebook pre-swizzled into MFMA B-fragment order (R9-verified):
  // e_frag[ct][b01][lane] = the f16x8 lane (nn=lane&15, quad=lane>>4) consumes
  // for code k=ct*16+nn, channels b01*32 + quad*8 + [0,8). +1 pad ct row.
  f16    e_frag[(64 + 1) * 2 * 64 * 8];
  // ---- per-half exact winners (gemm -> writer) ----
  float          hd[2 * NTOK];
  unsigned short hk[2 * NTOK];
};

// ---- eprep: e_norm (exact R1 chain) + channel sums + sum_e2 + fragments --
__global__ void vq_eprep(const float* __restrict__ emb, Ws* __restrict__ ws) {
  __shared__ float tile[64][68];
  __shared__ float red[256];
  const int tid = threadIdx.x;
  const int r = tid >> 2;                 // code row within block (0..63)
  const int q = tid & 3;                  // quarter of the 64-channel row
  const int k = blockIdx.x * 64 + r;
  const float4* src = (const float4*)(emb + (size_t)k * CH + q * 16);
  float4 a = src[0], b = src[1], c = src[2], d = src[3];
  float4* dst = (float4*)(&tile[r][q * 16]);
  dst[0] = a; dst[1] = b; dst[2] = c; dst[3] = d;
  float s2 = 0.f;
  s2 = fmaf(a.x,a.x,s2); s2 = fmaf(a.y,a.y,s2); s2 = fmaf(a.z,a.z,s2); s2 = fmaf(a.w,a.w,s2);
  s2 = fmaf(b.x,b.x,s2); s2 = fmaf(b.y,b.y,s2); s2 = fmaf(b.z,b.z,s2); s2 = fmaf(b.w,b.w,s2);
  s2 = fmaf(c.x,c.x,s2); s2 = fmaf(c.y,c.y,s2); s2 = fmaf(c.z,c.z,s2); s2 = fmaf(c.w,c.w,s2);
  s2 = fmaf(d.x,d.x,s2); s2 = fmaf(d.y,d.y,s2); s2 = fmaf(d.z,d.z,s2); s2 = fmaf(d.w,d.w,s2);
  // verified-exact row norm (R1-R10: absmax 0.0)
  float t1 = s2 + __shfl_xor(s2, 1);
  float t2 = t1 + __shfl_xor(t1, 2);
  if (q == 0) { ws->e_norm[k] = t2; ws->accI[k] = -0.5f * t2; }
  // pre-swizzled B-fragment write (R9-verified)
  {
    float vals[16] = {a.x,a.y,a.z,a.w, b.x,b.y,b.z,b.w,
                      c.x,c.y,c.z,c.w, d.x,d.y,d.z,d.w};
    const int ct  = blockIdx.x * 4 + (r >> 4);
    const int nn  = r & 15;
    const int b01 = q >> 1;
    const int qd0 = (q & 1) * 2;
    f16 h8a[8], h8b[8];
    #pragma unroll
    for (int u = 0; u < 8; ++u) { h8a[u] = (f16)vals[u]; h8b[u] = (f16)vals[8 + u]; }
    f16x8* fr = (f16x8*)ws->e_frag;
    fr[(ct * 2 + b01) * 64 + (qd0 + 0) * 16 + nn] = *(f16x8*)h8a;
    fr[(ct * 2 + b01) * 64 + (qd0 + 1) * 16 + nn] = *(f16x8*)h8b;
  }
  red[tid] = s2;
  __syncthreads();
  for (int off = 128; off > 0; off >>= 1) {
    if (tid < off) red[tid] += red[tid + off];
    __syncthreads();
  }
  if (tid == 0) atomicAdd(&ws->sum_e2, (double)red[0]);
  if (tid < CH) {
    float cs = 0.f;
    #pragma unroll 8
    for (int rr = 0; rr < 64; ++rr) cs += tile[rr][tid];
    atomicAdd(&ws->sum_e[tid], (double)cs);
  }
}

// ---- phase 1+2: MFMA candidates + exact per-half recheck (R10, verified) -
// grid 1024 = (512 token-groups) x (2 K-halves); block = 128 tokens x 512 codes
__global__ __launch_bounds__(256, 4)
void vq_gemm(const float* __restrict__ z, const float* __restrict__ emb,
             Ws* __restrict__ ws) {
  // LDS: [0,18432) zh (f16 z-tile), later reused as cand2 (uint2[128*17]=17408)
  //      [18432,19456) csh  [19456,20480) rd  [20480,21504) rk  [21504,23552) shs
  __shared__ char smem[23552];
  f16*          zh    = (f16*)smem;
  uint2*        cand2 = (uint2*)smem;
  unsigned int* csh   = (unsigned int*)(smem + 18432);
  float*        rd    = (float*)(smem + 19456);
  int*          rk    = (int*)(smem + 20480);
  float*        shs   = (float*)(smem + 21504);   // [512]: s, s2

  const int tid = threadIdx.x;
  const int h   = blockIdx.x & 1;          // K-half
  const int tg  = blockIdx.x >> 1;         // token group
  const int n0  = tg * 128;
  const int b   = n0 >> 14;
  const int s0  = n0 & 16383;
  const float* zbase = z + (size_t)b * (CH * DHWC) + s0;

  // stage z -> f16 [token][c] (stride 72); h==0 blocks also do channel sums
  {
    const int c = tid >> 2;            // 0..63
    const int q = tid & 3;             // token quarter
    const float4* src = (const float4*)(zbase + (size_t)c * DHWC) + q * 8;
    float ss = 0.f, ss2 = 0.f;
    #pragma unroll
    for (int i = 0; i < 8; ++i) {
      float4 v = src[i];
      const int t0 = q * 32 + i * 4;
      zh[(t0 + 0) * 72 + c] = (f16)v.x;
      zh[(t0 + 1) * 72 + c] = (f16)v.y;
      zh[(t0 + 2) * 72 + c] = (f16)v.z;
      zh[(t0 + 3) * 72 + c] = (f16)v.w;
      ss += v.x + v.y + v.z + v.w;
      ss2 = fmaf(v.x, v.x, ss2); ss2 = fmaf(v.y, v.y, ss2);
      ss2 = fmaf(v.z, v.z, ss2); ss2 = fmaf(v.w, v.w, ss2);
    }
    shs[tid] = ss; shs[256 + tid] = ss2;
  }
  __syncthreads();
  if (h == 0 && tid < 64) {
    float cs = shs[4*tid] + shs[4*tid+1] + shs[4*tid+2] + shs[4*tid+3];
    atomicAdd(&ws->sum_z[tid], cs);
    float cs2 = shs[256+4*tid] + shs[256+4*tid+1] + shs[256+4*tid+2] + shs[256+4*tid+3];
    #pragma unroll
    for (int off = 32; off > 0; off >>= 1) cs2 += __shfl_down(cs2, off);
    if (tid == 0) atomicAdd(&ws->sum_z2, (double)cs2);
  }

  const int lane = tid & 63;
  const int w    = tid >> 6;           // wave: tokens [w*32, w*32+32)
  const int nn   = lane & 15;          // MFMA column (code class)
  const int quad = lane >> 4;

  // A fragments (R4-R10-verified layout): A[m=lane&15][k=quad*8+j]
  f16x8 Ah[2][2];
  #pragma unroll
  for (int mt = 0; mt < 2; ++mt) {
    const int row = w * 32 + mt * 16 + nn;
    #pragma unroll
    for (int ks = 0; ks < 2; ++ks)
      Ah[mt][ks] = *(const f16x8*)(&zh[row * 72 + ks * 32 + quad * 8]);
  }

  // per-(token-slot, class) top-2 of (dot - enorm/2); argmax == argmin d
  float m1[8], m2[8]; int k1[8], k2[8];
  #pragma unroll
  for (int u = 0; u < 8; ++u) { m1[u] = -3.4e38f; m2[u] = -3.4e38f; k1[u] = 0; k2[u] = 0; }

  // B-fragments: lane-consecutive 16B -> ONE coalesced transaction per load
  const f16x8* __restrict__ fr  = ((const f16x8*)ws->e_frag) + lane;
  const float* __restrict__ aIp = ws->accI;

  int ct = h * 32;
  f16x8 B0 = fr[(ct * 2 + 0) * 64];
  f16x8 B1 = fr[(ct * 2 + 1) * 64];
  float ai = aIp[ct * 16 + nn];
  #pragma unroll 2
  for (int it = 0; it < 32; ++it) {
    const int nct = ct + 1;            // last prefetch hits the pad row
    f16x8 nB0 = fr[(nct * 2 + 0) * 64];
    f16x8 nB1 = fr[(nct * 2 + 1) * 64];
    const float nai = aIp[nct * 16 + nn];
    const int krow = ct * 16 + nn;
    fltx4 acc0 = {ai, ai, ai, ai};
    acc0 = __builtin_amdgcn_mfma_f32_16x16x32_f16(Ah[0][0], B0, acc0, 0, 0, 0);
    acc0 = __builtin_amdgcn_mfma_f32_16x16x32_f16(Ah[0][1], B1, acc0, 0, 0, 0);
    fltx4 acc1 = {ai, ai, ai, ai};
    acc1 = __builtin_amdgcn_mfma_f32_16x16x32_f16(Ah[1][0], B0, acc1, 0, 0, 0);
    acc1 = __builtin_amdgcn_mfma_f32_16x16x32_f16(Ah[1][1], B1, acc1, 0, 0, 0);
    #pragma unroll
    for (int r = 0; r < 4; ++r) {
      float a = acc0[r]; const int u = r;
      bool c1 = a > m1[u], c2 = a > m2[u];
      m2[u] = c1 ? m1[u] : (c2 ? a : m2[u]);
      k2[u] = c1 ? k1[u] : (c2 ? krow : k2[u]);
      m1[u] = c1 ? a : m1[u];
      k1[u] = c1 ? krow : k1[u];
    }
    #pragma unroll
    for (int r = 0; r < 4; ++r) {
      float a = acc1[r]; const int u = 4 + r;
      bool c1 = a > m1[u], c2 = a > m2[u];
      m2[u] = c1 ? m1[u] : (c2 ? a : m2[u]);
      k2[u] = c1 ? k1[u] : (c2 ? krow : k2[u]);
      m1[u] = c1 ? a : m1[u];
      k1[u] = c1 ? krow : k1[u];
    }
    ct = nct; B0 = nB0; B1 = nB1; ai = nai;
  }

  // pre-merge neighbor classes (lane^1): 16 classes -> 8 pairs, top-2 each
  #pragma unroll
  for (int u = 0; u < 8; ++u) {
    float om1 = __shfl_xor(m1[u], 1), om2 = __shfl_xor(m2[u], 1);
    int   ok1 = __shfl_xor(k1[u], 1), ok2 = __shfl_xor(k2[u], 1);
    bool af = (m1[u] > om1) || (m1[u] == om1 && k1[u] < ok1);
    float w1 = af ? m1[u] : om1;  int wk1 = af ? k1[u] : ok1;
    float s2v = af ? m2[u] : om2; int sk2 = af ? k2[u] : ok2;
    float l1 = af ? om1 : m1[u];  int lk1 = af ? ok1 : k1[u];
    bool sf = (s2v > l1) || (s2v == l1 && sk2 < lk1);
    m1[u] = w1; k1[u] = wk1;
    m2[u] = sf ? s2v : l1; k2[u] = sf ? sk2 : lk1;
  }

  __syncthreads();          // zh reads done; safe to overwrite as cand2
  if (!(nn & 1)) {
    const int p = nn >> 1;
    #pragma unroll
    for (int mt = 0; mt < 2; ++mt)
      #pragma unroll
      for (int r = 0; r < 4; ++r) {
        const int u = mt * 4 + r;
        const int tok = w * 32 + mt * 16 + quad * 4 + r;  // C/D row (verified)
        uint2 e1; e1.x = __float_as_uint(m1[u]); e1.y = (unsigned)k1[u];
        uint2 e2; e2.x = __float_as_uint(m2[u]); e2.y = (unsigned)k2[u];
        cand2[tok * 17 + p * 2 + 0] = e1;
        cand2[tok * 17 + p * 2 + 1] = e2;
      }
  }
  __syncthreads();

  // narrow 16 -> top-4 per token by (value desc, k asc)
  if (tid < 128) {
    float bv[4]; int bk[4];
    #pragma unroll
    for (int u = 0; u < 4; ++u) { bv[u] = -3.4e38f; bk[u] = 0x7fffffff; }
    #pragma unroll 4
    for (int i = 0; i < 16; ++i) {
      uint2 e = cand2[tid * 17 + i];
      float a = __uint_as_float(e.x);
      int   k = (int)e.y;
      #pragma unroll
      for (int j = 0; j < 4; ++j) {
        bool ins = (a > bv[j]) || (a == bv[j] && k < bk[j]);
        float ta = bv[j]; int tk = bk[j];
        bv[j] = ins ? a : bv[j]; bk[j] = ins ? k : bk[j];
        a = ins ? ta : a; k = ins ? tk : k;
      }
    }
    csh[tid * 2 + 0] = (unsigned)bk[0] | ((unsigned)bk[1] << 16);
    csh[tid * 2 + 1] = (unsigned)bk[2] | ((unsigned)bk[3] << 16);
  }
  __syncthreads();

  // exact recheck (R1 chain, float4 e-loads — R10-verified absmax 0)
  {
    const int t = tid & 127, half = tid >> 7;
    unsigned int cd = csh[t * 2 + half];
    const int ka = (int)(cd & 0xffff), kb = (int)(cd >> 16);
    const float4* ea4 = (const float4*)(emb + (size_t)ka * CH);
    const float4* eb4 = (const float4*)(emb + (size_t)kb * CH);
    const float* zt = zbase + t;
    float znorm = 0.f, da = 0.f, db = 0.f;
    #pragma unroll 4
    for (int c4 = 0; c4 < 16; ++c4) {
      float4 ev = ea4[c4];
      float4 fv = eb4[c4];
      float v0 = zt[(size_t)(4*c4+0) * DHWC];
      float v1 = zt[(size_t)(4*c4+1) * DHWC];
      float v2 = zt[(size_t)(4*c4+2) * DHWC];
      float v3 = zt[(size_t)(4*c4+3) * DHWC];
      znorm = fmaf(v0, v0, znorm); znorm = fmaf(v1, v1, znorm);
      znorm = fmaf(v2, v2, znorm); znorm = fmaf(v3, v3, znorm);
      da = fmaf(v0, ev.x, da); da = fmaf(v1, ev.y, da);
      da = fmaf(v2, ev.z, da); da = fmaf(v3, ev.w, da);
      db = fmaf(v0, fv.x, db); db = fmaf(v1, fv.y, db);
      db = fmaf(v2, fv.z, db); db = fmaf(v3, fv.w, db);
    }
    float dda = fmaf(-2.f, da, znorm + ws->e_norm[ka]);
    float ddb = fmaf(-2.f, db, znorm + ws->e_norm[kb]);
    bool pa = (dda < ddb) || (dda == ddb && ka < kb);
    rd[tid] = pa ? dda : ddb;
    rk[tid] = pa ? ka : kb;
  }
  __syncthreads();
  if (tid < 128) {
    float d0 = rd[tid], d1 = rd[tid + 128];
    int   q0 = rk[tid], q1 = rk[tid + 128];
    bool p = (d0 < d1) || (d0 == d1 && q0 < q1);
    ws->hd[h * NTOK + n0 + tid] = p ? d0 : d1;
    ws->hk[h * NTOK + n0 + tid] = (unsigned short)(p ? q0 : q1);
  }
}

// ---- phase 3: combine halves + output + loss + counts --------------------
// grid 256 x 1024; block = ONE (b,c) plane. One ecol staging per plane
// (256 stagings total — R9 had 512, R10 had 2048) at 16 waves/CU.
__global__ __launch_bounds__(1024, 4)
void vq_writer(const float* __restrict__ z, const float* __restrict__ emb,
               float* __restrict__ out, Ws* __restrict__ ws) {
  __shared__ float ecol[KCODES];     // column c of emb (4 KB)
  __shared__ int   hist[KCODES];     // LDS histogram (c==0 blocks only)
  __shared__ float sh[16];
  const int p   = blockIdx.x;        // plane: b*64 + c
  const int tid = threadIdx.x;
  const int b = p >> 6, c = p & 63;
  const bool docnt = (c == 0);
  // stage emb column c once per plane (1024 line-touches, amortized 16K elems)
  ecol[tid] = emb[(size_t)tid * CH + c];
  if (docnt) hist[tid] = 0;
  __syncthreads();

  const size_t base = (size_t)p * DHWC;
  const float4* zp = (const float4*)(z + base);
  float4* op = (float4*)(out + base);
  const int nbase = b * 16384;
  const float*          hd0 = ws->hd + nbase;
  const float*          hd1 = ws->hd + NTOK + nbase;
  const unsigned short* hk0 = ws->hk + nbase;
  const unsigned short* hk1 = ws->hk + NTOK + nbase;
  float lp = 0.f;
  #pragma unroll
  for (int i = tid; i < 4096; i += 1024) {         // 4 iterations
    float4 v  = zp[i];
    float4 d0 = *(const float4*)(hd0 + 4 * i);
    float4 d1 = *(const float4*)(hd1 + 4 * i);
    ushort4 ka = *(const ushort4*)(hk0 + 4 * i);
    ushort4 kb = *(const ushort4*)(hk1 + 4 * i);
    int w0 = (d0.x < d1.x || (d0.x == d1.x && ka.x < kb.x)) ? ka.x : kb.x;
    int w1 = (d0.y < d1.y || (d0.y == d1.y && ka.y < kb.y)) ? ka.y : kb.y;
    int w2 = (d0.z < d1.z || (d0.z == d1.z && ka.z < kb.z)) ? ka.z : kb.z;
    int w3 = (d0.w < d1.w || (d0.w == d1.w && ka.w < kb.w)) ? ka.w : kb.w;
    float q0 = ecol[w0], q1 = ecol[w1], q2 = ecol[w2], q3 = ecol[w3];
    float e0 = q0 - v.x, e1 = q1 - v.y, e2 = q2 - v.z, e3 = q3 - v.w;
    float4 o; o.x = v.x + e0; o.y = v.y + e1; o.z = v.z + e2; o.w = v.w + e3;
    op[i] = o;
    lp = fmaf(e0, e0, lp); lp = fmaf(e1, e1, lp);
    lp = fmaf(e2, e2, lp); lp = fmaf(e3, e3, lp);
    if (docnt) {                       // LDS atomics: no global contention
      atomicAdd(&hist[w0], 1);
      atomicAdd(&hist[w1], 1);
      atomicAdd(&hist[w2], 1);
      atomicAdd(&hist[w3], 1);
    }
  }
  // wave-shuffle loss reduction, then 16-entry LDS combine
  #pragma unroll
  for (int off = 32; off > 0; off >>= 1) lp += __shfl_down(lp, off);
  if ((tid & 63) == 0) sh[tid >> 6] = lp;
  __syncthreads();
  if (docnt) {
    int h2 = hist[tid];
    if (h2) atomicAdd(&ws->counts[tid], h2);
  }
  if (tid == 0) {
    float t = 0.f;
    #pragma unroll
    for (int i = 0; i < 16; ++i) t += sh[i];
    atomicAdd(&ws->loss_sum, (double)t);
  }
}

// ---- final: scalars ------------------------------------------------------
__global__ void vq_final(Ws* __restrict__ ws, float* __restrict__ out_scalars) {
  const int tid = threadIdx.x;
  float p = (float)ws->counts[tid] * (1.0f / 65536.0f);
  float term = p * logf(p + 1e-10f);
  __shared__ float sh[1024];
  sh[tid] = term;
  __syncthreads();
  for (int off = 512; off > 0; off >>= 1) {
    if (tid < off) sh[tid] += sh[tid + off];
    __syncthreads();
  }
  if (tid == 0) {
    float perp = expf(-sh[0]);
    double m = ws->loss_sum / (double)OUT_ELEMS;
    float mf = (float)m;
    float loss = mf + 0.25f * mf;
    double sdot = 0.0;
    #pragma unroll
    for (int c = 0; c < CH; ++c) sdot += (double)ws->sum_z[c] * ws->sum_e[c];
    double md = ws->sum_z2 / (double)NTOK + ws->sum_e2 / (double)KCODES
              - 2.0 * sdot / ((double)NTOK * (double)KCODES);
    out_scalars[0] = loss;
    out_scalars[1] = perp;
    out_scalars[2] = (float)md;
  }
}

extern "C" void kernel_launch(void* const* d_in, const int* in_sizes, int n_in,
                              void* d_out, int out_size, void* d_ws, size_t ws_size,
                              hipStream_t stream) {
  const float* z   = (const float*)d_in[0];
  const float* emb = (const float*)d_in[1];
  float* out = (float*)d_out;
  Ws* ws = (Ws*)d_ws;

  hipMemsetAsync(d_ws, 0, offsetof(Ws, e_norm), stream);
  vq_eprep <<<16,   256,  0, stream>>>(emb, ws);
  vq_gemm  <<<1024, 256,  0, stream>>>(z, emb, ws);
  vq_writer<<<256,  1024, 0, stream>>>(z, emb, out, ws);
  vq_final <<<1,    1024, 0, stream>>>(ws, out + OUT_ELEMS);
}